// Round 7
// baseline (588.068 us; speedup 1.0000x reference)
//
#include <hip/hip_runtime.h>
#include <hip/hip_bf16.h>
#include <stdint.h>

// ---------------------------------------------------------------------------
// PropagationRWKV: LN -> (k,v,r) GEMM -> channel-decay scan -> y GEMM -> out
// B=8, N=16384, C=256. M = 131072 rows.
// R6 (re-run; prior bench was an infra failure, no signal): barrier-free
// full-K GEMM.
//   Post-mortem R5: 512-B-stride LDS tiles conflict (3.1M cycles, 4/read);
//   per-ks B-gathers don't hide L2 latency at 2 waves/SIMD. And across
//   R0/R3 the binding cost was LDS-read redundancy (2m x 4n wave grid reads
//   A 4x, B 2x from LDS) + vmcnt(0) barrier drains on 4 shallow K-steps.
//   New structure: block = 256m x fullK. A staged ONCE into 4 proven-
//   conflict-free [256][64] LDS panels (one __syncthreads total); 8 waves
//   stacked in m (wave 32m x 64n) -> A read from LDS exactly once, no
//   redundancy, zero interior barriers. B held in 128 VGPRs per 64-wide
//   n-pass (loaded once per pass from L2/L3, reused over all K). n looped
//   inside the block (12 passes gemm0, 4 gemm1): A hits HBM exactly once
//   chip-wide; XCD swizzle no longer needed (blocks share nothing).
// ---------------------------------------------------------------------------

typedef __attribute__((ext_vector_type(8))) short short8;
typedef __attribute__((ext_vector_type(4))) short short4v;
typedef __attribute__((ext_vector_type(4))) float f32x4;

static __device__ __forceinline__ unsigned short f2bf(float f) {
  __hip_bfloat16 h = __float2bfloat16(f);
  return *reinterpret_cast<unsigned short*>(&h);
}
static __device__ __forceinline__ float bf2f(unsigned short u) {
  unsigned int v = ((unsigned int)u) << 16;
  float f;
  __builtin_memcpy(&f, &v, 4);
  return f;
}

// ---------------------------------------------------------------------------
// Kernel 1: LayerNorm fp32 -> bf16.  One wave per row (C=256, float4/lane).
// ---------------------------------------------------------------------------
__global__ void ln_kernel(const float* __restrict__ x,
                          const float* __restrict__ w,
                          const float* __restrict__ b,
                          unsigned short* __restrict__ xn) {
  const int wv = threadIdx.x >> 6;
  const int ln = threadIdx.x & 63;
  const size_t row = (size_t)blockIdx.x * 4 + wv;
  const float4 v = reinterpret_cast<const float4*>(x)[row * 64 + ln];
  float s  = v.x + v.y + v.z + v.w;
  float sq = v.x * v.x + v.y * v.y + v.z * v.z + v.w * v.w;
#pragma unroll
  for (int off = 32; off; off >>= 1) {
    s  += __shfl_xor(s, off, 64);
    sq += __shfl_xor(sq, off, 64);
  }
  const float mu  = s * (1.0f / 256.0f);
  const float var = sq * (1.0f / 256.0f) - mu * mu;
  const float rs  = rsqrtf(var + 1e-5f);
  const float4 w4 = reinterpret_cast<const float4*>(w)[ln];
  const float4 b4 = reinterpret_cast<const float4*>(b)[ln];
  ushort4 o;
  o.x = f2bf((v.x - mu) * rs * w4.x + b4.x);
  o.y = f2bf((v.y - mu) * rs * w4.y + b4.y);
  o.z = f2bf((v.z - mu) * rs * w4.z + b4.z);
  o.w = f2bf((v.w - mu) * rs * w4.w + b4.w);
  reinterpret_cast<ushort4*>(xn)[row * 64 + ln] = o;
}

// ---------------------------------------------------------------------------
// Kernel 2: convert weights fp32 -> bf16. Wkvr = [Wk;Wv;Wr] rows 0..767.
// ---------------------------------------------------------------------------
__global__ void cvt_weights(const float* __restrict__ Wk,
                            const float* __restrict__ Wv,
                            const float* __restrict__ Wr,
                            const float* __restrict__ Wo,
                            unsigned short* __restrict__ Wkvr,
                            unsigned short* __restrict__ Wob) {
  const int idx = blockIdx.x * 256 + threadIdx.x;  // 0 .. 1024*256
  if (idx < 768 * 256) {
    const int r = idx >> 8;
    const int c = idx & 255;
    const float* src = (r < 256) ? Wk : ((r < 512) ? Wv : Wr);
    Wkvr[idx] = f2bf(src[(r & 255) * 256 + c]);
  } else {
    const int j = idx - 768 * 256;
    Wob[j] = f2bf(Wo[j]);
  }
}

// ---------------------------------------------------------------------------
// Barrier-free MFMA GEMM: C[m][n] = sum_k A[m][k] * Bt[n][k], K=256.
// Block = 256 m-rows, full K. 8 waves stacked in m; wave tile 32m x 64n
// (mt=2, nt=4 of 16x16x32, operand-swapped -> Ct, 4 consecutive n per reg).
// A: 4 LDS panels [256][64] (128-B row stride, R3-proven conflict-free XOR
//    swizzle), staged once via global_load_lds, single __syncthreads.
// B: 32 x short8 in VGPRs per n-pass (Bf[8][4], fully static-indexed),
//    gathered from L2/L3 once per pass, reused across all 4 K-panels.
// n-passes of 64 cols: NPASS=12 (gemm0, N=768) / 4 (gemm1, N=256).
// EPI 0: k/v/sigmoid(r) bf16 split epilogue. EPI 1: fp32 out.
// ---------------------------------------------------------------------------
template <int EPI, int NPASS>
__global__ __launch_bounds__(512, 2) void gemm_bt(
    const unsigned short* __restrict__ A,
    const unsigned short* __restrict__ Bt,
    unsigned short* __restrict__ kbuf,
    unsigned short* __restrict__ vbuf,
    unsigned short* __restrict__ rbuf,
    float* __restrict__ outf) {
  __shared__ unsigned short Als[4][256][64];  // 128 KiB

  const int tid = threadIdx.x;
  const int wv = tid >> 6;      // 0..7
  const int ln = tid & 63;
  const int lq = ln >> 4;       // 0..3
  const int lm = ln & 15;
  const size_t mrow = (size_t)blockIdx.x * 256;   // block m-base

  // ---- Stage A full-K once: panel p holds K-cols [p*64, p*64+64).
  // Wave wv stages rows [wv*32, wv*32+32) of every panel (4 groups of 8).
  {
    const int srow = ln >> 3;             // 0..7
    const int schunk = (ln & 7) ^ srow;   // pre-swizzled source chunk
#pragma unroll
    for (int p = 0; p < 4; ++p) {
#pragma unroll
      for (int i = 0; i < 4; ++i) {
        const int r0 = wv * 32 + i * 8;
        const unsigned short* gA =
            A + (mrow + r0 + srow) * 256 + p * 64 + schunk * 8;
        __builtin_amdgcn_global_load_lds(
            (const __attribute__((address_space(1))) void*)gA,
            (__attribute__((address_space(3))) void*)&Als[p][r0][0], 16, 0, 0);
      }
    }
  }
  __syncthreads();  // the ONLY barrier: drains staging, then waves run free

  const int mw = wv * 32;   // wave m-offset inside the block

  for (int ns = 0; ns < NPASS; ++ns) {
    const int nb = ns * 64;   // n-slice base (global col for EPI1)

    // ---- B fragments for this n-slice: Bf[ks][nt], ks = K/32 slice.
    short8 Bf[8][4];
#pragma unroll
    for (int ks = 0; ks < 8; ++ks)
#pragma unroll
      for (int nt = 0; nt < 4; ++nt)
        Bf[ks][nt] = *reinterpret_cast<const short8*>(
            Bt + (size_t)(nb + nt * 16 + lm) * 256 + ks * 32 + lq * 8);

    f32x4 acc[2][4];
#pragma unroll
    for (int t = 0; t < 2; ++t)
#pragma unroll
      for (int nt = 0; nt < 4; ++nt) acc[t][nt] = (f32x4){0.f, 0.f, 0.f, 0.f};

    // ---- K loop: 4 panels x 2 halves of 32.
#pragma unroll
    for (int p = 0; p < 4; ++p) {
#pragma unroll
      for (int h = 0; h < 2; ++h) {
        const int ks = p * 2 + h;
        short8 af[2];
#pragma unroll
        for (int t = 0; t < 2; ++t) {
          const int row = mw + t * 16 + lm;
          const int chunk = (h * 4 + lq) ^ (row & 7);
          af[t] = *reinterpret_cast<const short8*>(&Als[p][row][chunk * 8]);
        }
#pragma unroll
        for (int t = 0; t < 2; ++t)
#pragma unroll
          for (int nt = 0; nt < 4; ++nt)
            acc[t][nt] = __builtin_amdgcn_mfma_f32_16x16x32_bf16(
                Bf[ks][nt], af[t], acc[t][nt], 0, 0, 0);
      }
    }

    // ---- Epilogue for this n-slice (Ct layout: lane col=m, regs span n).
#pragma unroll
    for (int t = 0; t < 2; ++t) {
      const size_t m_g = mrow + mw + t * 16 + lm;
#pragma unroll
      for (int nt = 0; nt < 4; ++nt) {
        f32x4 a = acc[t][nt];
        if (EPI == 0) {
          const int bufi = nb >> 8;              // block-pass-uniform
          const int col = (nb & 255) + nt * 16 + lq * 4;
          unsigned short* dst = (bufi == 0) ? kbuf : ((bufi == 1) ? vbuf : rbuf);
          if (bufi == 2) {
#pragma unroll
            for (int r = 0; r < 4; ++r) a[r] = 1.0f / (1.0f + __expf(-a[r]));
          }
          ushort4 pk;
          pk.x = f2bf(a[0]); pk.y = f2bf(a[1]); pk.z = f2bf(a[2]); pk.w = f2bf(a[3]);
          *reinterpret_cast<ushort4*>(&dst[m_g * 256 + col]) = pk;
        } else {
          const int col = nb + nt * 16 + lq * 4;
          float4 o = make_float4(a[0], a[1], a[2], a[3]);
          *reinterpret_cast<float4*>(&outf[m_g * 256 + col]) = o;
        }
      }
    }
  }
}

// ---------------------------------------------------------------------------
// Scan decomposition: NCHUNK=256 chunks of L=64 per batch (2048 chunks).
// Pass A: per-chunk local carry. One 64-lane wave per chunk, 4 ch/lane.
// ---------------------------------------------------------------------------
__global__ void scan_carry(const unsigned short* __restrict__ k,
                           const float* __restrict__ td,
                           float* __restrict__ carry) {
  const int ln = threadIdx.x & 63;
  const int w = threadIdx.x >> 6;                 // 4 chunks per block
  const int bch = blockIdx.x * 4 + w;             // 0 .. 2047
  const int c0 = ln * 4;
  float d[4], s[4];
#pragma unroll
  for (int j = 0; j < 4; ++j) {
    d[j] = expf(-fmaxf(td[c0 + j], 0.0f));
    s[j] = 0.0f;
  }
  const unsigned short* kp = k + (size_t)bch * 64 * 256 + c0;
#pragma unroll 8
  for (int i = 0; i < 64; ++i) {
    short4v kv = *reinterpret_cast<const short4v*>(kp + (size_t)i * 256);
#pragma unroll
    for (int j = 0; j < 4; ++j) s[j] = s[j] * d[j] + bf2f((unsigned short)kv[j]);
  }
  *reinterpret_cast<float4*>(carry + (size_t)bch * 256 + c0) =
      make_float4(s[0], s[1], s[2], s[3]);
}

// ---------------------------------------------------------------------------
// Pass B: exclusive scan of chunk carries per batch (in-place), 8-wide
// load prefetch to break the serial latency chain.
// ---------------------------------------------------------------------------
__global__ void scan_chunks(float* __restrict__ carry,
                            const float* __restrict__ td) {
  const int b = blockIdx.x;
  const int c = threadIdx.x;
  const float dL = expf(-fmaxf(td[c], 0.0f) * 64.0f);
  float s = 0.0f;
  float* base = carry + (size_t)b * 256 * 256 + c;  // 256 chunks, stride 256
  for (int j0 = 0; j0 < 256; j0 += 8) {
    float buf[8];
#pragma unroll
    for (int t = 0; t < 8; ++t) buf[t] = base[(size_t)(j0 + t) * 256];
#pragma unroll
    for (int t = 0; t < 8; ++t) {
      base[(size_t)(j0 + t) * 256] = s;
      s = dL * s + buf[t];
    }
  }
}

// ---------------------------------------------------------------------------
// Pass C: recompute states with carry-in, y = r*(state+v) -> bf16 over k.
// One 64-lane wave per chunk, 4 ch/lane; 512 blocks (2 blocks/CU).
// ---------------------------------------------------------------------------
__global__ void scan_final(unsigned short* __restrict__ k,
                           const unsigned short* __restrict__ v,
                           const unsigned short* __restrict__ r,
                           const float* __restrict__ carryin,
                           const float* __restrict__ td) {
  const int ln = threadIdx.x & 63;
  const int w = threadIdx.x >> 6;
  const int bch = blockIdx.x * 4 + w;
  const int c0 = ln * 4;
  float d[4], s[4];
  const float4 ci = *reinterpret_cast<const float4*>(
      carryin + (size_t)bch * 256 + c0);
  s[0] = ci.x; s[1] = ci.y; s[2] = ci.z; s[3] = ci.w;
#pragma unroll
  for (int j = 0; j < 4; ++j) d[j] = expf(-fmaxf(td[c0 + j], 0.0f));
  const size_t base = (size_t)bch * 64 * 256 + c0;
#pragma unroll 4
  for (int i = 0; i < 64; ++i) {
    const size_t off = base + (size_t)i * 256;
    short4v kv = *reinterpret_cast<const short4v*>(k + off);
    short4v vv = *reinterpret_cast<const short4v*>(v + off);
    short4v rv = *reinterpret_cast<const short4v*>(r + off);
    short4v y;
#pragma unroll
    for (int j = 0; j < 4; ++j) {
      s[j] = s[j] * d[j] + bf2f((unsigned short)kv[j]);
      const float yj = bf2f((unsigned short)rv[j]) * (s[j] + bf2f((unsigned short)vv[j]));
      y[j] = (short)f2bf(yj);
    }
    *reinterpret_cast<short4v*>(k + off) = y;
  }
}

// ---------------------------------------------------------------------------
extern "C" void kernel_launch(void* const* d_in, const int* in_sizes, int n_in,
                              void* d_out, int out_size, void* d_ws, size_t ws_size,
                              hipStream_t stream) {
  const float* x   = (const float*)d_in[0];
  const float* td  = (const float*)d_in[1];
  const float* Wk  = (const float*)d_in[2];
  const float* Wv  = (const float*)d_in[3];
  const float* Wr  = (const float*)d_in[4];
  const float* Wo  = (const float*)d_in[5];
  const float* lnw = (const float*)d_in[6];
  const float* lnb = (const float*)d_in[7];
  float* out = (float*)d_out;

  const int Bsz = 8, C = 256;
  const size_t M = 131072;  // B*N

  char* ws = (char*)d_ws;
  size_t off = 0;
  auto alloc = [&](size_t bytes) -> char* {
    char* p = ws + off;
    off += (bytes + 255) & ~(size_t)255;
    return p;
  };
  unsigned short* xn   = (unsigned short*)alloc(M * C * 2);
  unsigned short* kbuf = (unsigned short*)alloc(M * C * 2);  // later holds y
  unsigned short* vbuf = (unsigned short*)alloc(M * C * 2);
  unsigned short* rbuf = (unsigned short*)alloc(M * C * 2);
  unsigned short* Wkvr = (unsigned short*)alloc(768 * 256 * 2);
  unsigned short* Wob  = (unsigned short*)alloc(256 * 256 * 2);
  float* carry = (float*)alloc((size_t)Bsz * 256 * C * 4);
  (void)ws_size; (void)in_sizes; (void)n_in; (void)out_size;

  cvt_weights<<<dim3(1024), dim3(256), 0, stream>>>(Wk, Wv, Wr, Wo, Wkvr, Wob);
  ln_kernel<<<dim3((unsigned)(M / 4)), dim3(256), 0, stream>>>(x, lnw, lnb, xn);
  // g0: 512 blocks of 256 m-rows, 12 n-passes of 64 (N=768).
  gemm_bt<0, 12><<<dim3(512), dim3(512), 0, stream>>>(
      xn, Wkvr, kbuf, vbuf, rbuf, nullptr);
  scan_carry<<<dim3(512), dim3(256), 0, stream>>>(kbuf, td, carry);
  scan_chunks<<<dim3(Bsz), dim3(256), 0, stream>>>(carry, td);
  scan_final<<<dim3(512), dim3(256), 0, stream>>>(kbuf, vbuf, rbuf, carry, td);
  // g1: 512 blocks, 4 n-passes (N=256).
  gemm_bt<1, 4><<<dim3(512), dim3(512), 0, stream>>>(
      kbuf, Wob, nullptr, nullptr, nullptr, out);
}

// Round 8
// 445.016 us; speedup vs baseline: 1.3215x; 1.3215x over previous
//
#include <hip/hip_runtime.h>
#include <hip/hip_bf16.h>
#include <stdint.h>

// ---------------------------------------------------------------------------
// PropagationRWKV: LN -> (k,v,r) GEMM -> channel-decay scan -> y GEMM -> out
// B=8, N=16384, C=256. M = 131072 rows.
// R7: RESET to measured-best after three failed gemm redesigns (R3 105,
//     R5 151, R6 210 vs R0 98.7 -- R6 failed because the compiler remat'd
//     the 128-VGPR B array into per-MFMA L2 loads, VGPR_Count=88 proved it).
//     gemm_bt: byte-identical to the 440.3us R0 version (128x128/4-wave,
//     64-K-step, A+B staged, n-fastest grid, NO swizzle).
//     Banked low-risk wins: scan_carry/scan_final at 2 blocks/CU (R5
//     variants, correctness-proven), ln_kernel grid-strided at 2048 blocks.
// ---------------------------------------------------------------------------

typedef __attribute__((ext_vector_type(8))) short short8;
typedef __attribute__((ext_vector_type(4))) short short4v;
typedef __attribute__((ext_vector_type(4))) float f32x4;

static __device__ __forceinline__ unsigned short f2bf(float f) {
  __hip_bfloat16 h = __float2bfloat16(f);
  return *reinterpret_cast<unsigned short*>(&h);
}
static __device__ __forceinline__ float bf2f(unsigned short u) {
  unsigned int v = ((unsigned int)u) << 16;
  float f;
  __builtin_memcpy(&f, &v, 4);
  return f;
}

// ---------------------------------------------------------------------------
// Kernel 1: LayerNorm fp32 -> bf16.  One wave per row (C=256, float4/lane).
// Grid-strided: 2048 blocks x 4 waves, 16 rows per wave (G11: cap grid,
// stride the rest; loads across iterations are independent -> ILP).
// ---------------------------------------------------------------------------
__global__ void ln_kernel(const float* __restrict__ x,
                          const float* __restrict__ w,
                          const float* __restrict__ b,
                          unsigned short* __restrict__ xn) {
  const int wv = threadIdx.x >> 6;
  const int ln = threadIdx.x & 63;
  const float4 w4 = reinterpret_cast<const float4*>(w)[ln];
  const float4 b4 = reinterpret_cast<const float4*>(b)[ln];
  const size_t M = 131072;
  for (size_t row = (size_t)blockIdx.x * 4 + wv; row < M; row += 4 * 2048) {
    const float4 v = reinterpret_cast<const float4*>(x)[row * 64 + ln];
    float s  = v.x + v.y + v.z + v.w;
    float sq = v.x * v.x + v.y * v.y + v.z * v.z + v.w * v.w;
#pragma unroll
    for (int off = 32; off; off >>= 1) {
      s  += __shfl_xor(s, off, 64);
      sq += __shfl_xor(sq, off, 64);
    }
    const float mu  = s * (1.0f / 256.0f);
    const float var = sq * (1.0f / 256.0f) - mu * mu;
    const float rs  = rsqrtf(var + 1e-5f);
    ushort4 o;
    o.x = f2bf((v.x - mu) * rs * w4.x + b4.x);
    o.y = f2bf((v.y - mu) * rs * w4.y + b4.y);
    o.z = f2bf((v.z - mu) * rs * w4.z + b4.z);
    o.w = f2bf((v.w - mu) * rs * w4.w + b4.w);
    reinterpret_cast<ushort4*>(xn)[row * 64 + ln] = o;
  }
}

// ---------------------------------------------------------------------------
// Kernel 2: convert weights fp32 -> bf16. Wkvr = [Wk;Wv;Wr] rows 0..767.
// ---------------------------------------------------------------------------
__global__ void cvt_weights(const float* __restrict__ Wk,
                            const float* __restrict__ Wv,
                            const float* __restrict__ Wr,
                            const float* __restrict__ Wo,
                            unsigned short* __restrict__ Wkvr,
                            unsigned short* __restrict__ Wob) {
  const int idx = blockIdx.x * 256 + threadIdx.x;  // 0 .. 1024*256
  if (idx < 768 * 256) {
    const int r = idx >> 8;
    const int c = idx & 255;
    const float* src = (r < 256) ? Wk : ((r < 512) ? Wv : Wr);
    Wkvr[idx] = f2bf(src[(r & 255) * 256 + c]);
  } else {
    const int j = idx - 768 * 256;
    Wob[j] = f2bf(Wo[j]);
  }
}

// ---------------------------------------------------------------------------
// MFMA GEMM: C[m][n] = sum_k A[m][k] * Bt[n][k].
// 128x128 tile / block, 4 waves, 64x64 per wave (4x4 of 16x16x32 MFMA).
// Operand-SWAPPED mfma (computes Ct fragments): lane holds 4 CONSECUTIVE n
// per acc -> 8B bf16 / 16B fp32 stores.
// Grid is 1D, n-fastest (id%NY) so n-slices of one m-tile share A in L2.
// EPI 0: split k/v/sigmoid(r) bf16 epilogue. EPI 1: fp32 out.
// (Byte-identical to the measured 440.3us / 98.7us-gemm0 R0 version.)
// ---------------------------------------------------------------------------
template <int EPI, int NY>
__global__ void gemm_bt(const unsigned short* __restrict__ A,
                        const unsigned short* __restrict__ Bt,
                        unsigned short* __restrict__ kbuf,
                        unsigned short* __restrict__ vbuf,
                        unsigned short* __restrict__ rbuf,
                        float* __restrict__ outf) {
  constexpr int K = 256;
  __shared__ unsigned short Als[128][64];  // 16 KiB, swizzled 16B chunks
  __shared__ unsigned short Bls[128][64];  // 16 KiB

  const int tid = threadIdx.x;
  const int wv = tid >> 6;
  const int ln = tid & 63;
  const int bid = blockIdx.x;
  const int bm0 = (bid / NY) * 128;
  const int bn0 = (bid % NY) * 128;
  const int lq = ln >> 4;   // quad 0..3
  const int lm = ln & 15;

  f32x4 acc[4][4];
#pragma unroll
  for (int i = 0; i < 4; ++i)
#pragma unroll
    for (int j = 0; j < 4; ++j) acc[i][j] = (f32x4){0.f, 0.f, 0.f, 0.f};

  const int m0w = (wv >> 1) * 64;
  const int n0w = (wv & 1) * 64;

  const int srow = ln >> 3;              // 0..7 (row within 8-row group)
  const int schunk = (ln & 7) ^ srow;    // swizzled source chunk

  for (int kk0 = 0; kk0 < K; kk0 += 64) {
#pragma unroll
    for (int i = 0; i < 4; ++i) {
      const int rr = wv * 32 + i * 8;    // wave-uniform base row
      const unsigned short* gA = A + (size_t)(bm0 + rr + srow) * K + kk0 + schunk * 8;
      __builtin_amdgcn_global_load_lds(
          (const __attribute__((address_space(1))) void*)gA,
          (__attribute__((address_space(3))) void*)&Als[rr][0], 16, 0, 0);
      const unsigned short* gB = Bt + (size_t)(bn0 + rr + srow) * K + kk0 + schunk * 8;
      __builtin_amdgcn_global_load_lds(
          (const __attribute__((address_space(1))) void*)gB,
          (__attribute__((address_space(3))) void*)&Bls[rr][0], 16, 0, 0);
    }
    __syncthreads();
#pragma unroll
    for (int kk = 0; kk < 64; kk += 32) {
      short8 af[4], bfr[4];
      const int chunk = (kk >> 3) + lq;  // 0..3 or 4..7
#pragma unroll
      for (int t = 0; t < 4; ++t) {
        const int rowa = m0w + t * 16 + lm;
        af[t] = *reinterpret_cast<const short8*>(&Als[rowa][(chunk ^ (rowa & 7)) * 8]);
        const int rowb = n0w + t * 16 + lm;
        bfr[t] = *reinterpret_cast<const short8*>(&Bls[rowb][(chunk ^ (rowb & 7)) * 8]);
      }
      // Swapped operands: computes Ct. Lane holds col=m (lm), rows = 4
      // consecutive n (lq*4 + reg).
#pragma unroll
      for (int mt = 0; mt < 4; ++mt)
#pragma unroll
        for (int nt = 0; nt < 4; ++nt)
          acc[mt][nt] = __builtin_amdgcn_mfma_f32_16x16x32_bf16(
              bfr[nt], af[mt], acc[mt][nt], 0, 0, 0);
    }
    __syncthreads();
  }

  // Epilogue (Ct layout): m = ...+lm, n_base = ...+lq*4, regs span n.
#pragma unroll
  for (int mt = 0; mt < 4; ++mt) {
    const int m_g = bm0 + m0w + mt * 16 + lm;
#pragma unroll
    for (int nt = 0; nt < 4; ++nt) {
      const int n_base = bn0 + n0w + nt * 16 + lq * 4;
      f32x4 a = acc[mt][nt];
      if (EPI == 0) {
        const int bufi = n_base >> 8;   // uniform within a 16-wide nt tile
        const int col = n_base & 255;
        unsigned short* dst = (bufi == 0) ? kbuf : ((bufi == 1) ? vbuf : rbuf);
        if (bufi == 2) {
#pragma unroll
          for (int r = 0; r < 4; ++r) a[r] = 1.0f / (1.0f + __expf(-a[r]));
        }
        ushort4 pk;
        pk.x = f2bf(a[0]); pk.y = f2bf(a[1]); pk.z = f2bf(a[2]); pk.w = f2bf(a[3]);
        *reinterpret_cast<ushort4*>(&dst[(size_t)m_g * 256 + col]) = pk;
      } else {
        float4 o = make_float4(a[0], a[1], a[2], a[3]);
        *reinterpret_cast<float4*>(&outf[(size_t)m_g * 256 + n_base]) = o;
      }
    }
  }
}

// ---------------------------------------------------------------------------
// Scan decomposition: NCHUNK=256 chunks of L=64 per batch (2048 chunks).
// Pass A: per-chunk local carry. One 64-lane wave per chunk, 4 ch/lane.
// 512 blocks x 256 threads -> 2 blocks/CU (8 waves/CU, was 1 block/CU).
// ---------------------------------------------------------------------------
__global__ void scan_carry(const unsigned short* __restrict__ k,
                           const float* __restrict__ td,
                           float* __restrict__ carry) {
  const int ln = threadIdx.x & 63;
  const int w = threadIdx.x >> 6;                 // 4 chunks per block
  const int bch = blockIdx.x * 4 + w;             // 0 .. 2047
  const int c0 = ln * 4;
  float d[4], s[4];
#pragma unroll
  for (int j = 0; j < 4; ++j) {
    d[j] = expf(-fmaxf(td[c0 + j], 0.0f));
    s[j] = 0.0f;
  }
  const unsigned short* kp = k + (size_t)bch * 64 * 256 + c0;
#pragma unroll 8
  for (int i = 0; i < 64; ++i) {
    short4v kv = *reinterpret_cast<const short4v*>(kp + (size_t)i * 256);
#pragma unroll
    for (int j = 0; j < 4; ++j) s[j] = s[j] * d[j] + bf2f((unsigned short)kv[j]);
  }
  *reinterpret_cast<float4*>(carry + (size_t)bch * 256 + c0) =
      make_float4(s[0], s[1], s[2], s[3]);
}

// ---------------------------------------------------------------------------
// Pass B: exclusive scan of chunk carries per batch (in-place), 8-wide
// load prefetch to break the serial latency chain.
// ---------------------------------------------------------------------------
__global__ void scan_chunks(float* __restrict__ carry,
                            const float* __restrict__ td) {
  const int b = blockIdx.x;
  const int c = threadIdx.x;
  const float dL = expf(-fmaxf(td[c], 0.0f) * 64.0f);
  float s = 0.0f;
  float* base = carry + (size_t)b * 256 * 256 + c;  // 256 chunks, stride 256
  for (int j0 = 0; j0 < 256; j0 += 8) {
    float buf[8];
#pragma unroll
    for (int t = 0; t < 8; ++t) buf[t] = base[(size_t)(j0 + t) * 256];
#pragma unroll
    for (int t = 0; t < 8; ++t) {
      base[(size_t)(j0 + t) * 256] = s;
      s = dL * s + buf[t];
    }
  }
}

// ---------------------------------------------------------------------------
// Pass C: recompute states with carry-in, y = r*(state+v) -> bf16 over k.
// One 64-lane wave per chunk, 4 ch/lane; 512 blocks (2 blocks/CU).
// ---------------------------------------------------------------------------
__global__ void scan_final(unsigned short* __restrict__ k,
                           const unsigned short* __restrict__ v,
                           const unsigned short* __restrict__ r,
                           const float* __restrict__ carryin,
                           const float* __restrict__ td) {
  const int ln = threadIdx.x & 63;
  const int w = threadIdx.x >> 6;
  const int bch = blockIdx.x * 4 + w;
  const int c0 = ln * 4;
  float d[4], s[4];
  const float4 ci = *reinterpret_cast<const float4*>(
      carryin + (size_t)bch * 256 + c0);
  s[0] = ci.x; s[1] = ci.y; s[2] = ci.z; s[3] = ci.w;
#pragma unroll
  for (int j = 0; j < 4; ++j) d[j] = expf(-fmaxf(td[c0 + j], 0.0f));
  const size_t base = (size_t)bch * 64 * 256 + c0;
#pragma unroll 4
  for (int i = 0; i < 64; ++i) {
    const size_t off = base + (size_t)i * 256;
    short4v kv = *reinterpret_cast<const short4v*>(k + off);
    short4v vv = *reinterpret_cast<const short4v*>(v + off);
    short4v rv = *reinterpret_cast<const short4v*>(r + off);
    short4v y;
#pragma unroll
    for (int j = 0; j < 4; ++j) {
      s[j] = s[j] * d[j] + bf2f((unsigned short)kv[j]);
      const float yj = bf2f((unsigned short)rv[j]) * (s[j] + bf2f((unsigned short)vv[j]));
      y[j] = (short)f2bf(yj);
    }
    *reinterpret_cast<short4v*>(k + off) = y;
  }
}

// ---------------------------------------------------------------------------
extern "C" void kernel_launch(void* const* d_in, const int* in_sizes, int n_in,
                              void* d_out, int out_size, void* d_ws, size_t ws_size,
                              hipStream_t stream) {
  const float* x   = (const float*)d_in[0];
  const float* td  = (const float*)d_in[1];
  const float* Wk  = (const float*)d_in[2];
  const float* Wv  = (const float*)d_in[3];
  const float* Wr  = (const float*)d_in[4];
  const float* Wo  = (const float*)d_in[5];
  const float* lnw = (const float*)d_in[6];
  const float* lnb = (const float*)d_in[7];
  float* out = (float*)d_out;

  const int Bsz = 8, C = 256;
  const size_t M = 131072;  // B*N

  char* ws = (char*)d_ws;
  size_t off = 0;
  auto alloc = [&](size_t bytes) -> char* {
    char* p = ws + off;
    off += (bytes + 255) & ~(size_t)255;
    return p;
  };
  unsigned short* xn   = (unsigned short*)alloc(M * C * 2);
  unsigned short* kbuf = (unsigned short*)alloc(M * C * 2);  // later holds y
  unsigned short* vbuf = (unsigned short*)alloc(M * C * 2);
  unsigned short* rbuf = (unsigned short*)alloc(M * C * 2);
  unsigned short* Wkvr = (unsigned short*)alloc(768 * 256 * 2);
  unsigned short* Wob  = (unsigned short*)alloc(256 * 256 * 2);
  float* carry = (float*)alloc((size_t)Bsz * 256 * C * 4);
  (void)ws_size; (void)in_sizes; (void)n_in; (void)out_size;

  cvt_weights<<<dim3(1024), dim3(256), 0, stream>>>(Wk, Wv, Wr, Wo, Wkvr, Wob);
  ln_kernel<<<dim3(2048), dim3(256), 0, stream>>>(x, lnw, lnb, xn);
  gemm_bt<0, 6><<<dim3(1024 * 6), dim3(256), 0, stream>>>(
      xn, Wkvr, kbuf, vbuf, rbuf, nullptr);
  scan_carry<<<dim3(512), dim3(256), 0, stream>>>(kbuf, td, carry);
  scan_chunks<<<dim3(Bsz), dim3(256), 0, stream>>>(carry, td);
  scan_final<<<dim3(512), dim3(256), 0, stream>>>(kbuf, vbuf, rbuf, carry, td);
  gemm_bt<1, 2><<<dim3(1024 * 2), dim3(256), 0, stream>>>(
      kbuf, Wob, nullptr, nullptr, nullptr, out);
}